// Round 7
// baseline (401.113 us; speedup 1.0000x reference)
//
#include <hip/hip_runtime.h>
#include <stdint.h>

#define NN 10000
#define NE 160000
#define MPAD 10112   // 79 * 128 = 158 * 64
#define MTILES 79

typedef unsigned short u16;
typedef float f32x4 __attribute__((ext_vector_type(4)));
typedef short short8 __attribute__((ext_vector_type(8)));
typedef __bf16 bf16x8 __attribute__((ext_vector_type(8)));
typedef unsigned short u16x4 __attribute__((ext_vector_type(4)));
typedef unsigned short u16x8 __attribute__((ext_vector_type(8)));

__device__ __forceinline__ float bf2f(u16 u) {
  union { unsigned u; float f; } c; c.u = ((unsigned)u) << 16; return c.f;
}
__device__ __forceinline__ u16 f2bf(float f) {
  union { float f; unsigned u; } c; c.f = f;
  return (u16)((c.u + 0x7FFFu + ((c.u >> 16) & 1u)) >> 16);
}

// ---------------- CSR build ----------------
__global__ __launch_bounds__(256) void deg_count(const int* __restrict__ dst, int* __restrict__ deg) {
  int e = blockIdx.x * 256 + threadIdx.x;
  if (e < NE) atomicAdd(&deg[dst[e]], 1);
}

__global__ __launch_bounds__(256) void scan_off(const int* __restrict__ deg,
                                                int* __restrict__ roff, int* __restrict__ cur) {
  __shared__ int part[256];
  const int t = threadIdx.x;
  const int CH = 40;
  int s = 0;
  for (int i = 0; i < CH; ++i) { int idx = t * CH + i; if (idx < NN) s += deg[idx]; }
  part[t] = s; __syncthreads();
  for (int off = 1; off < 256; off <<= 1) {
    int v = (t >= off) ? part[t - off] : 0;
    __syncthreads(); part[t] += v; __syncthreads();
  }
  int run = (t == 0) ? 0 : part[t - 1];
  for (int i = 0; i < CH; ++i) {
    int idx = t * CH + i;
    if (idx < NN) { roff[idx] = run; cur[idx] = run; run += deg[idx]; }
  }
  if (t == 255) roff[NN] = NE;
}

__global__ __launch_bounds__(256) void fill_csr(const int* __restrict__ src, const int* __restrict__ dst,
                                                int* __restrict__ cur, int* __restrict__ esrc) {
  int e = blockIdx.x * 256 + threadIdx.x;
  if (e < NE) {
    int p = atomicAdd(&cur[dst[e]], 1);
    esrc[p] = src[e];
  }
}

// ---------------- conversions ----------------
__global__ __launch_bounds__(256) void convert_h(const float* __restrict__ h, u16* __restrict__ hbf) {
  const size_t i = (size_t)(blockIdx.x * 256 + threadIdx.x) * 4;
  if (i >= (size_t)MPAD * 960) return;
  u16x4 o;
  if (i < (size_t)NN * 960) {
    float4 v = *(const float4*)(h + i);
    o[0] = f2bf(v.x); o[1] = f2bf(v.y); o[2] = f2bf(v.z); o[3] = f2bf(v.w);
  } else {
    o[0] = 0; o[1] = 0; o[2] = 0; o[3] = 0;
  }
  *(u16x4*)(hbf + i) = o;
}

// weight transposes, K-concat capable: out[c*ldo + koff + r] = bf16(in[r][c])
struct WDesc { const float* in; u16* out; int R, C, Cpad, ldo, koff; };
struct WPack { WDesc d[7]; };

__global__ __launch_bounds__(256) void transpose_all(WPack p) {
  const WDesc w = p.d[blockIdx.z];
  const int cb = blockIdx.x * 32, rb = blockIdx.y * 32;
  if (cb >= w.Cpad || rb >= w.R) return;
  __shared__ float tile[32][33];
  const int tx = threadIdx.x & 31, ty = threadIdx.x >> 5;
  for (int i = ty; i < 32; i += 8) {
    int r = rb + i, c = cb + tx;
    tile[i][tx] = (r < w.R && c < w.C) ? w.in[(size_t)r * w.C + c] : 0.f;
  }
  __syncthreads();
  for (int i = ty; i < 32; i += 8) {
    int c = cb + i, r = rb + tx;
    if (c < w.Cpad && r < w.R) w.out[(size_t)c * w.ldo + w.koff + r] = f2bf(tile[tx][i]);
  }
}

// ---------------- GEMM: Cb = act(([A0|A1]) @ B^T + bias) ----------------
// Model after rounds 0-5: gemm time == one block's serial phase chain;
// cadence set by the global_load_lds DMA unit (~one 1KB instr per ~190cy,
// serialized block-wide; invariant to wave count and instrs/wave). This
// version bypasses the DMA unit: reg-staging (T14):
// global_load_dwordx4 -> VGPR -> ds_write_b128 (plain VMEM loads pipeline
// many-outstanding per wave).
// ROUND-6 BUG (fixed): loop ran phases in unguarded pairs assuming even
// nsteps, but G1 has K=960 -> nsteps=15 ODD; the phantom phase(15) re-read
// S1 (still holding tile 13) and accumulated K-slice 13 TWICE -> +6.7% on
// m0 -> 1.17e-2 final absmax. Fix: `if (base+1 < nsteps)` guard (phase
// identity stays compile-time static).
// Pipeline: 8 waves, BK=64, two 32KB buffers, ONE barrier per phase:
//   barrier          // S[t&1]=tile t visible; prev readers of S[(t+1)&1] done
//   ds_read tile t   // 12 x b128
//   gload t+2 -> set[t&1]          (4 x dwordx4, linear, coalesced)
//   vmcnt(4)         // set[(t+1)&1] (tile t+1, issued last phase) landed
//   ds_write set[(t+1)&1] -> S[(t+1)&1]
//   lgkmcnt(0)       // frags in regs + writes retired
//   MFMA x16
// Buffer safety: S[(t+1)&1]'s readers (phase t-1) drained lgkm before this
// phase's barrier. Reg sets rA/rB alternate by static phase parity (rule
// #20). Swizzle applied on the ds_write address (phys slot = sslot ^
// (row&7)); global source LINEAR; ds_read side same XOR involution.
template<int TM, int TN, int MINW>
__global__ __launch_bounds__(512, MINW) void gemm3(
    const u16* __restrict__ A0, int lda0,
    const u16* __restrict__ A1, int lda1, int ksplit,
    const u16* __restrict__ B,
    const float* __restrict__ bias, int nbias,
    u16* __restrict__ Cb, int ldcb,
    int K, int act, int tiles_n) {
  constexpr int TR = TM + TN;        // staged rows per K-tile (256)
  constexpr int WCOLS = 4;           // 8 waves: 2 rows x 4 cols
  constexpr int WN = TN / WCOLS;     // 32
  constexpr int NJ = WN / 16;        // 2
  constexpr int MT = MPAD / TM;      // M tiles
  __shared__ __align__(16) u16 S0[TR * 64];
  __shared__ __align__(16) u16 S1[TR * 64];
  const int tid = threadIdx.x;
  const int wave = tid >> 6, lane = tid & 63;

  // bijective XCD-chunked swizzle over col-fastest linear id (m204)
  const int nwg = tiles_n * MT;
  const int orig = blockIdx.x + blockIdx.y * tiles_n;
  const int q = nwg >> 3, r8 = nwg & 7;
  const int xcd = orig & 7, idx = orig >> 3;
  const int wg = (xcd < r8 ? xcd * (q + 1) : r8 * (q + 1) + (xcd - r8) * q) + idx;
  const int tm = (wg / tiles_n) * TM;
  const int tn = (wg % tiles_n) * TN;

  const int wr = (wave / WCOLS) * 64;
  const int wc = (wave % WCOLS) * WN;
  const int fr = lane & 15, fq = lane >> 4;
  const int sr8 = lane >> 3;         // row within 8-row wave chunk
  const int sslot = lane & 7;        // 16B slot within 128B row
  f32x4 acc[4][NJ] = {};

  const int nsteps = K >> 6;          // BK=64; K % 64 == 0 in all uses

  // linear coalesced global loads: lanes 0..7 sweep one 128B row
  auto gloadv = [&](u16x8 (&r)[4], int kk) {
#pragma unroll
    for (int c = 0; c < 4; ++c) {
      const int row = c * 64 + wave * 8 + sr8;
      if (c < TM / 64) {                                      // A rows
        r[c] = (kk < ksplit)
            ? *(const u16x8*)&A0[(size_t)(tm + row) * lda0 + kk + sslot * 8]
            : *(const u16x8*)&A1[(size_t)(tm + row) * lda1 + (kk - ksplit) + sslot * 8];
      } else {                                                // B rows
        r[c] = *(const u16x8*)&B[(size_t)(tn + row - TM) * (size_t)K + kk + sslot * 8];
      }
    }
  };
  // swizzled LDS write: phys slot = sslot ^ (row&7); row&7 == sr8
  auto dswrite = [&](u16* Sw, u16x8 (&r)[4]) {
#pragma unroll
    for (int c = 0; c < 4; ++c) {
      const int row = c * 64 + wave * 8 + sr8;
      *(u16x8*)&Sw[row * 64 + ((sslot ^ sr8) << 3)] = r[c];
    }
  };

  u16x8 rA[4], rB[4];
  gloadv(rA, 0);                      // tile 0
  asm volatile("s_waitcnt vmcnt(0)" ::: "memory");
  dswrite(S0, rA);
  gloadv(rB, 64);                     // tile 1 (nsteps >= 8 always)
  asm volatile("s_waitcnt lgkmcnt(0)" ::: "memory");  // S0 writes retired

  // one phase; wset holds raw tile t+1 (to write), lset receives tile t+2
  auto phase = [&](int t, const u16* Sr, u16* Sw,
                   u16x8 (&wset)[4], u16x8 (&lset)[4]) {
    __builtin_amdgcn_s_barrier();     // tile t visible; Sw readers sealed
    __builtin_amdgcn_sched_barrier(0);
    short8 af[4][2], bfr[2][NJ];
#pragma unroll
    for (int i = 0; i < 4; ++i) {
      const int r = wr + i * 16 + fr;
#pragma unroll
      for (int kc = 0; kc < 2; ++kc)
        af[i][kc] = *(const short8*)&Sr[r * 64 + ((((kc << 2) | fq) ^ (r & 7)) << 3)];
    }
#pragma unroll
    for (int j = 0; j < NJ; ++j) {
      const int r = TM + wc + j * 16 + fr;
#pragma unroll
      for (int kc = 0; kc < 2; ++kc)
        bfr[kc][j] = *(const short8*)&Sr[r * 64 + ((((kc << 2) | fq) ^ (r & 7)) << 3)];
    }
    __builtin_amdgcn_sched_barrier(0);
    if (t + 2 < nsteps) gloadv(lset, (t + 2) << 6);
    __builtin_amdgcn_sched_barrier(0);
    if (t + 1 < nsteps) {
      if (t + 2 < nsteps) {
        asm volatile("s_waitcnt vmcnt(4)" ::: "memory");  // wset landed; lset in flight
      } else {
        asm volatile("s_waitcnt vmcnt(0)" ::: "memory");
      }
      dswrite(Sw, wset);
    }
    asm volatile("s_waitcnt lgkmcnt(0)" ::: "memory");  // frags ready + writes retired
    __builtin_amdgcn_sched_barrier(0);
    __builtin_amdgcn_s_setprio(1);
#pragma unroll
    for (int kc = 0; kc < 2; ++kc)
#pragma unroll
      for (int i = 0; i < 4; ++i)
#pragma unroll
        for (int j = 0; j < NJ; ++j)
          acc[i][j] = __builtin_amdgcn_mfma_f32_16x16x32_bf16(
              __builtin_bit_cast(bf16x8, af[i][kc]), __builtin_bit_cast(bf16x8, bfr[kc][j]),
              acc[i][j], 0, 0, 0);
    __builtin_amdgcn_s_setprio(0);
    __builtin_amdgcn_sched_barrier(0);
  };

  for (int base = 0; base < nsteps; base += 2) {
    phase(base, S0, S1, rB, rA);                       // write t+1 (rB), load t+2 -> rA
    if (base + 1 < nsteps)                             // K=960 -> nsteps=15 is ODD
      phase(base + 1, S1, S0, rA, rB);                 // write t+2 (rA), load t+3 -> rB
  }

  // C/D layout: col=lane&15, row=(lane>>4)*4+reg (m89/m91 verified)
  const int cr = fq * 4, cc = fr;
#pragma unroll
  for (int i = 0; i < 4; ++i)
#pragma unroll
    for (int j = 0; j < NJ; ++j) {
      const int col = tn + wc + j * 16 + cc;
      const float bv = (col < nbias) ? bias[col] : 0.f;
#pragma unroll
      for (int r = 0; r < 4; ++r) {
        const int row = tm + wr + i * 16 + cr + r;
        float v = acc[i][j][r] + bv;
        if (act) v = fmaxf(v, 0.f);
        Cb[(size_t)row * ldcb + col] = f2bf(v);
      }
    }
}

// ---------------- segment max, XCD feature-sliced ----------------
// Feature dim split into 8 slices of CW; slice c pinned to XCD c via
// blockIdx.x & 7. Per-XCD working set MPAD*CW*2B = 2.6MB/1.3MB < 4MB L2.
// relu'd bf16 >= 0: u16 compare == float compare; 0 == empty-segment fill.
template<int CW>
__global__ __launch_bounds__(256) void aggregate_xcd(
    const u16* __restrict__ m, int ldm, const int* __restrict__ roff,
    const int* __restrict__ esrc, u16* __restrict__ neigh, int ldn) {
  constexpr int TPN = CW / 8;          // threads per node
  constexpr int NPB = 256 / TPN;       // nodes per block
  const int chunk = blockIdx.x & 7;
  const int node = (blockIdx.x >> 3) * NPB + threadIdx.x / TPN;
  if (node >= NN) return;
  const int fi = chunk * CW + (threadIdx.x % TPN) * 8;
  const int beg = roff[node], end = roff[node + 1];
  u16x8 a;
#pragma unroll
  for (int i = 0; i < 8; ++i) a[i] = 0;
  for (int e = beg; e < end; ++e) {
    const u16* row = m + (size_t)esrc[e] * ldm;
    u16x8 v = *(const u16x8*)(row + fi);
#pragma unroll
    for (int i = 0; i < 8; ++i) a[i] = (v[i] > a[i]) ? v[i] : a[i];
  }
  *(u16x8*)(neigh + (size_t)node * ldn + fi) = a;
}

// ---------------- layer 2 output: sigmoid(x2 . Ws2 + neigh2 . Wn2 + b2) ----------------
__global__ __launch_bounds__(256) void final_out(
    const u16* __restrict__ x, const u16* __restrict__ neigh,
    const float* __restrict__ ws, const float* __restrict__ wn,
    const float* __restrict__ b, float* __restrict__ out) {
  const int wave = threadIdx.x >> 6, lane = threadIdx.x & 63;
  const int n = blockIdx.x * 4 + wave;
  if (n >= NN) return;
  const int f = lane * 8;
  const u16* xr = x + (size_t)n * 512 + f;
  const u16* nr = neigh + (size_t)n * 512 + f;
  float s = 0.f;
#pragma unroll
  for (int i = 0; i < 8; ++i)
    s += bf2f(xr[i]) * ws[f + i] + bf2f(nr[i]) * wn[f + i];
#pragma unroll
  for (int o = 32; o > 0; o >>= 1) s += __shfl_xor(s, o);
  if (lane == 0) out[n] = 1.f / (1.f + expf(-(s + b[0])));
}

extern "C" void kernel_launch(void* const* d_in, const int* in_sizes, int n_in,
                              void* d_out, int out_size, void* d_ws, size_t ws_size,
                              hipStream_t stream) {
  const float* h   = (const float*)d_in[0];
  const int*   src = (const int*)d_in[1];
  const int*   dst = (const int*)d_in[2];
  const float* Wp0 = (const float*)d_in[3];
  const float* bp0 = (const float*)d_in[4];
  const float* Ws0 = (const float*)d_in[5];
  const float* Wn0 = (const float*)d_in[6];
  const float* b0  = (const float*)d_in[7];
  const float* Wp1 = (const float*)d_in[8];
  const float* bp1 = (const float*)d_in[9];
  const float* Ws1 = (const float*)d_in[10];
  const float* Wn1 = (const float*)d_in[11];
  const float* b1  = (const float*)d_in[12];
  const float* Wp2 = (const float*)d_in[13];
  const float* bp2 = (const float*)d_in[14];
  const float* Ws2 = (const float*)d_in[15];
  const float* Wn2 = (const float*)d_in[16];
  const float* b2  = (const float*)d_in[17];
  float* out = (float*)d_out;

  char* ws = (char*)d_ws;
  size_t off = 0;
  auto alloc = [&](size_t n) { char* p = ws + off; off = (off + n + 255) & ~(size_t)255; return p; };
  u16* hbf   = (u16*)alloc((size_t)MPAD * 960 * 2);
  u16* x1    = (u16*)alloc((size_t)MPAD * 512 * 2);
  u16* x2    = (u16*)alloc((size_t)MPAD * 512 * 2);
  u16* mbuf  = (u16*)alloc((size_t)MPAD * 1024 * 2);
  u16* nbuf  = (u16*)alloc((size_t)MPAD * 1024 * 2);
  u16* WpT0  = (u16*)alloc((size_t)1024 * 960 * 2);   // [1024 cols][K=960]
  u16* Bcat0 = (u16*)alloc((size_t)512 * 1920 * 2);   // [512][Ws0(960) ; Wn0(960)]
  u16* WpT1  = (u16*)alloc((size_t)512 * 512 * 2);
  u16* Bcat1 = (u16*)alloc((size_t)512 * 1024 * 2);   // [512][Ws1(512) ; Wn1(512)]
  u16* WpT2  = (u16*)alloc((size_t)512 * 512 * 2);
  int* deg   = (int*)alloc(NN * 4);
  int* roff  = (int*)alloc((NN + 1) * 4);
  int* curp  = (int*)alloc(NN * 4);
  int* esrc  = (int*)alloc(NE * 4);

  hipMemsetAsync(deg, 0, NN * 4, stream);
  deg_count<<<NE / 256, 256, 0, stream>>>(dst, deg);
  scan_off<<<1, 256, 0, stream>>>(deg, roff, curp);
  fill_csr<<<NE / 256, 256, 0, stream>>>(src, dst, curp, esrc);
  convert_h<<<(MPAD * 960 / 4) / 256, 256, 0, stream>>>(h, hbf);

  WPack wp;
  wp.d[0] = {Wp0, WpT0,  960, 960, 1024,  960,   0};
  wp.d[1] = {Ws0, Bcat0, 960, 512,  512, 1920,   0};
  wp.d[2] = {Wn0, Bcat0, 960, 512,  512, 1920, 960};
  wp.d[3] = {Wp1, WpT1,  512, 512,  512,  512,   0};
  wp.d[4] = {Ws1, Bcat1, 512, 512,  512, 1024,   0};
  wp.d[5] = {Wn1, Bcat1, 512, 512,  512, 1024, 512};
  wp.d[6] = {Wp2, WpT2,  512, 512,  512,  512,   0};
  transpose_all<<<dim3(32, 30, 7), 256, 0, stream>>>(wp);

  // ---- layer 0 (960 -> 512) ----
  // G1: m0 = relu(hbf @ Wp0 + bp0)  [N=1024 padded, 960 real]
  gemm3<128, 128, 4><<<dim3(8, 79), 512, 0, stream>>>(
      hbf, 960, hbf, 960, 960, WpT0, bp0, 960, mbuf, 1024, 960, 1, 8);
  aggregate_xcd<128><<<5000, 256, 0, stream>>>(mbuf, 1024, roff, esrc, nbuf, 1024);
  // G2: x1 = relu([hbf | nbuf] @ [Ws0;Wn0] + b0)  K = 1920
  gemm3<128, 128, 4><<<dim3(4, 79), 512, 0, stream>>>(
      hbf, 960, nbuf, 1024, 960, Bcat0, b0, 512, x1, 512, 1920, 1, 4);

  // ---- layer 1 (512 -> 512) ----
  gemm3<128, 128, 4><<<dim3(4, 79), 512, 0, stream>>>(
      x1, 512, x1, 512, 512, WpT1, bp1, 512, mbuf, 512, 512, 1, 4);
  aggregate_xcd<64><<<2504, 256, 0, stream>>>(mbuf, 512, roff, esrc, nbuf, 512);
  gemm3<128, 128, 4><<<dim3(4, 79), 512, 0, stream>>>(
      x1, 512, nbuf, 512, 512, Bcat1, b1, 512, x2, 512, 1024, 1, 4);

  // ---- layer 2 (512 -> 1) ----
  gemm3<128, 128, 4><<<dim3(4, 79), 512, 0, stream>>>(
      x2, 512, x2, 512, 512, WpT2, bp2, 512, mbuf, 512, 512, 1, 4);
  aggregate_xcd<64><<<2504, 256, 0, stream>>>(mbuf, 512, roff, esrc, nbuf, 512);
  final_out<<<2500, 256, 0, stream>>>(x2, nbuf, Ws2, Wn2, b2, out);
}